// Round 1
// baseline (218.968 us; speedup 1.0000x reference)
//
#include <hip/hip_runtime.h>
#include <float.h>

// FeatPropagation k=3 NN interpolation, round 6.
// R5 post-mortem: scalarized (s_load) point stream stalls ~55% of cycles:
// SMEM returns out-of-order so the compiler must wait lgkmcnt(0) before each
// consume, draining the prefetch too (SGPR double-buffer defeated); scalar K$
// thrashes across 8x8KiB streams/block. Real VALU busy ~43% (gfx950 derived
// VALUBusy is ~2x inflated), vs a ~65us VALU floor for phase A.
// R6: stage the batch's 4096 packed points (64 KiB) into LDS once per block;
// inner loop reads wave-uniform ds_read_b128 broadcasts (in-order, counted
// lgkmcnt, ~64-cyc latency fully hidden by the existing group double-buffer).
// LDS 79,360 B -> 2 blocks/CU (4 waves/SIMD) which saturates VALU issue.
// Phase B unroll 2->4 to keep gather MLP with fewer resident waves.
//
// PROTECTED (absmax 0.015625, 4.7x under threshold): d2 computed as
// (q2+s2) - 2*((qx*sx+qy*sy)+qz*sz) with __fmul_rn/__fadd_rn per-op rounding
// in this exact order; strict < via packed (d2,idx) key min; ties -> lower
// index. Do NOT switch to fma/dx^2 form.

#define QPB   64   // queries per block-wave group (== wave width)
#define SPLIT 8    // candidate chunks per block == waves per block
#define KEY_INIT 0x7FEFFFFFFFFFFFFFULL  // > any real packed key

__global__ void pack_pts(const float* __restrict__ xyz,
                         float4* __restrict__ pts, int total) {
    int i = blockIdx.x * blockDim.x + threadIdx.x;
    if (i < total) {
        const float sx = xyz[(size_t)i * 3 + 0];
        const float sy = xyz[(size_t)i * 3 + 1];
        const float sz = xyz[(size_t)i * 3 + 2];
        const float s2 = __fadd_rn(__fadd_rn(__fmul_rn(sx, sx), __fmul_rn(sy, sy)),
                                   __fmul_rn(sz, sz));
        pts[i] = make_float4(sx, sy, sz, s2);
    }
}

__device__ __forceinline__ double mk_key(float d2, int j) {
    unsigned long long u =
        ((unsigned long long)(unsigned)__float_as_uint(d2) << 32) | (unsigned)j;
    return __longlong_as_double(u);
}

template <int CHUNK>
__global__ __launch_bounds__(512, 4) void fp_knn_main(
    const float* __restrict__ new_xyz,   // [B*M, 3]
    const float4* __restrict__ pts,      // [B*N] packed (x,y,z,s2)
    const float4* __restrict__ feat4,    // [B*N, 64]  (C=256)
    float4* __restrict__ out4,           // [B*M, 64]
    int N, int blocks_per_batch)
{
    __shared__ float4 s_pts[SPLIT * CHUNK];  // 64 KiB: whole batch, packed
    __shared__ double s_k[SPLIT][QPB][3];    // 12 KiB
    __shared__ float  s_w[QPB][3];
    __shared__ int    s_j[QPB][3];

    int g = blockIdx.x;
    // XCD swizzle (bijective, grid 1024): batch b's 256 blocks -> XCDs {2b,2b+1}
    // so its 4 MiB feat slab stays in one XCD pair's L2.
    if (gridDim.x == 1024 && blocks_per_batch == 256) {
        const int xcd = g & 7, slot = g >> 3;        // slot in [0,128)
        g = (xcd >> 1) * 256 + (xcd & 1) * 128 + slot;
    }

    const int tid = threadIdx.x;
    const int q   = tid & (QPB - 1);   // query within block (lane)
    const int b   = g / blocks_per_batch;
    const int src_base = b * N;
    const int m = g * QPB + q;         // global query index

    const float qx = new_xyz[(size_t)m * 3 + 0];
    const float qy = new_xyz[(size_t)m * 3 + 1];
    const float qz = new_xyz[(size_t)m * 3 + 2];
    const float q2 = __fadd_rn(__fadd_rn(__fmul_rn(qx, qx), __fmul_rn(qy, qy)),
                               __fmul_rn(qz, qz));

    // ---- stage the batch's point cloud into LDS (coalesced, once) ----
    {
        const float4* __restrict__ gp = pts + src_base;
        #pragma unroll
        for (int i = 0; i < (SPLIT * CHUNK) / 512; ++i)
            s_pts[i * 512 + tid] = gp[i * 512 + tid];
    }
    __syncthreads();

    // Wave-uniform chunk id: each wave scans its own 512-point LDS chunk with
    // uniform-address ds_read_b128 broadcasts (in-order, counted lgkmcnt).
    const int s_u   = __builtin_amdgcn_readfirstlane(tid >> 6);  // 0..7
    const int cbase = s_u * CHUNK;
    const float4* __restrict__ cp = s_pts + cbase;

    double k0 = __longlong_as_double(KEY_INIT);
    double k1 = k0, k2 = k0;

    constexpr int G  = 4;
    constexpr int NG = CHUNK / G;      // 128 groups
    float4 buf[2][G];

    #pragma unroll
    for (int t = 0; t < G; ++t) buf[0][t] = cp[t];

    auto process = [&](const float4 p, int cj) {
        const float cross = __fadd_rn(
            __fadd_rn(__fmul_rn(qx, p.x), __fmul_rn(qy, p.y)),
            __fmul_rn(qz, p.z));
        const float d2 = __fadd_rn(q2, p.w) - (cross + cross);
        const double key = mk_key(d2, cj);
        const double n0 = fmin(key, k0);
        const double n1 = fmin(fmax(key, k0), k1);
        const double n2 = fmin(fmax(key, k1), k2);
        k0 = n0; k1 = n1; k2 = n2;
    };

    #pragma unroll 2
    for (int gi = 0; gi < NG - 1; ++gi) {
        const float4* nx = cp + (gi + 1) * G;
        #pragma unroll
        for (int t = 0; t < G; ++t) buf[(gi + 1) & 1][t] = nx[t];
        #pragma unroll
        for (int t = 0; t < G; ++t)
            process(buf[gi & 1][t], cbase + gi * G + t);
    }
    #pragma unroll
    for (int t = 0; t < G; ++t)
        process(buf[(NG - 1) & 1][t], cbase + (NG - 1) * G + t);

    s_k[s_u][q][0] = k0; s_k[s_u][q][1] = k1; s_k[s_u][q][2] = k2;
    __syncthreads();

    // ---- 24-way merge per query on packed keys (1 wave, tie-exact) ----
    if (tid < QPB) {
        double m0 = __longlong_as_double(KEY_INIT), m1 = m0, m2 = m0;
        #pragma unroll
        for (int ss = 0; ss < SPLIT; ++ss) {
            #pragma unroll
            for (int r = 0; r < 3; ++r) {
                const double d = s_k[ss][tid][r];
                const double n0 = fmin(d, m0);
                const double n1 = fmin(fmax(d, m0), m1);
                const double n2 = fmin(fmax(d, m1), m2);
                m0 = n0; m1 = n1; m2 = n2;
            }
        }
        unsigned long long u0 = __double_as_longlong(m0);
        unsigned long long u1 = __double_as_longlong(m1);
        unsigned long long u2 = __double_as_longlong(m2);
        const float d0 = __uint_as_float((unsigned)(u0 >> 32));
        const float d1 = __uint_as_float((unsigned)(u1 >> 32));
        const float d2 = __uint_as_float((unsigned)(u2 >> 32));
        const float e0 = sqrtf(fmaxf(d0, 1e-12f));
        const float e1 = sqrtf(fmaxf(d1, 1e-12f));
        const float e2 = sqrtf(fmaxf(d2, 1e-12f));
        const float r0 = 1.0f / (e0 + 1e-8f);
        const float r1 = 1.0f / (e1 + 1e-8f);
        const float r2 = 1.0f / (e2 + 1e-8f);
        const float rs = r0 + r1 + r2;
        s_w[tid][0] = r0 / rs; s_w[tid][1] = r1 / rs; s_w[tid][2] = r2 / rs;
        s_j[tid][0] = (int)(u0 & 0xffffffffu);
        s_j[tid][1] = (int)(u1 & 0xffffffffu);
        s_j[tid][2] = (int)(u2 & 0xffffffffu);
    }
    __syncthreads();

    // ---- phase B: gather + interpolate; each of 8 waves handles 8 queries ----
    const int lane  = tid & 63;
    const int wv    = tid >> 6;
    const int qbase = g * QPB;
    #pragma unroll 4
    for (int t = 0; t < QPB / SPLIT; ++t) {
        const int qq = wv * (QPB / SPLIT) + t;
        const int   a0 = s_j[qq][0], a1 = s_j[qq][1], a2 = s_j[qq][2];
        const float u0 = s_w[qq][0], u1 = s_w[qq][1], u2 = s_w[qq][2];
        const float4 f0 = feat4[(size_t)(src_base + a0) * 64 + lane];
        const float4 f1 = feat4[(size_t)(src_base + a1) * 64 + lane];
        const float4 f2 = feat4[(size_t)(src_base + a2) * 64 + lane];
        float4 o;
        o.x = u0 * f0.x + u1 * f1.x + u2 * f2.x;
        o.y = u0 * f0.y + u1 * f1.y + u2 * f2.y;
        o.z = u0 * f0.z + u1 * f1.z + u2 * f2.z;
        o.w = u0 * f0.w + u1 * f1.w + u2 * f2.w;
        out4[(size_t)(qbase + qq) * 64 + lane] = o;
    }
}

// Generic fallback (shape mismatch only) — same semantics, unoptimized.
__global__ void fp_knn_generic(
    const float* __restrict__ new_xyz, const float* __restrict__ xyz,
    const float* __restrict__ feat, float* __restrict__ out,
    int N, int M, int Btot)
{
    const int m = blockIdx.x * blockDim.x + threadIdx.x;
    if (m >= Btot * M) return;
    const int b = m / M;
    const int src_base = b * N;
    const float qx = new_xyz[(size_t)m * 3 + 0];
    const float qy = new_xyz[(size_t)m * 3 + 1];
    const float qz = new_xyz[(size_t)m * 3 + 2];
    const float q2 = __fadd_rn(__fadd_rn(__fmul_rn(qx, qx), __fmul_rn(qy, qy)),
                               __fmul_rn(qz, qz));
    double k0 = __longlong_as_double(KEY_INIT), k1 = k0, k2 = k0;
    for (int j = 0; j < N; ++j) {
        const float sx = xyz[(size_t)(src_base + j) * 3 + 0];
        const float sy = xyz[(size_t)(src_base + j) * 3 + 1];
        const float sz = xyz[(size_t)(src_base + j) * 3 + 2];
        const float s2 = __fadd_rn(__fadd_rn(__fmul_rn(sx, sx), __fmul_rn(sy, sy)),
                                   __fmul_rn(sz, sz));
        const float cross = __fadd_rn(
            __fadd_rn(__fmul_rn(qx, sx), __fmul_rn(qy, sy)), __fmul_rn(qz, sz));
        const float d2 = __fadd_rn(q2, s2) - (cross + cross);
        const double key = mk_key(d2, j);
        const double n0 = fmin(key, k0);
        const double n1 = fmin(fmax(key, k0), k1);
        const double n2 = fmin(fmax(key, k1), k2);
        k0 = n0; k1 = n1; k2 = n2;
    }
    unsigned long long u0 = __double_as_longlong(k0);
    unsigned long long u1 = __double_as_longlong(k1);
    unsigned long long u2 = __double_as_longlong(k2);
    const float e0 = sqrtf(fmaxf(__uint_as_float((unsigned)(u0 >> 32)), 1e-12f));
    const float e1 = sqrtf(fmaxf(__uint_as_float((unsigned)(u1 >> 32)), 1e-12f));
    const float e2 = sqrtf(fmaxf(__uint_as_float((unsigned)(u2 >> 32)), 1e-12f));
    const float r0 = 1.0f / (e0 + 1e-8f);
    const float r1 = 1.0f / (e1 + 1e-8f);
    const float r2 = 1.0f / (e2 + 1e-8f);
    const float rs = r0 + r1 + r2;
    const float w0 = r0 / rs, w1 = r1 / rs, w2 = r2 / rs;
    const int a0 = (int)(u0 & 0xffffffffu), a1 = (int)(u1 & 0xffffffffu),
              a2 = (int)(u2 & 0xffffffffu);
    const int C = 256;
    for (int c = 0; c < C; ++c) {
        out[(size_t)m * C + c] =
            w0 * feat[(size_t)(src_base + a0) * C + c] +
            w1 * feat[(size_t)(src_base + a1) * C + c] +
            w2 * feat[(size_t)(src_base + a2) * C + c];
    }
}

extern "C" void kernel_launch(void* const* d_in, const int* in_sizes, int n_in,
                              void* d_out, int out_size, void* d_ws, size_t ws_size,
                              hipStream_t stream) {
    const float* xyz     = (const float*)d_in[0];
    const float* new_xyz = (const float*)d_in[1];
    const float* feat    = (const float*)d_in[2];
    float* out = (float*)d_out;

    const int B = in_sizes[3];                 // 4
    const int N = in_sizes[0] / (3 * B);       // 4096
    const int M = in_sizes[1] / (3 * B);       // 16384

    const size_t need = (size_t)(B * N) * sizeof(float4);  // 256 KiB
    const bool fast = (N % SPLIT == 0) && (N / SPLIT == 512) &&
                      (M % QPB == 0) && (ws_size >= need);
    if (fast) {
        pack_pts<<<(B * N + 255) / 256, 256, 0, stream>>>(xyz, (float4*)d_ws, B * N);
        const int blocks = (B * M) / QPB;      // 1024
        fp_knn_main<512><<<blocks, 512, 0, stream>>>(
            new_xyz, (const float4*)d_ws, (const float4*)feat, (float4*)out,
            N, M / QPB);
    } else {
        fp_knn_generic<<<(B * M + 255) / 256, 256, 0, stream>>>(
            new_xyz, xyz, feat, out, N, M, B);
    }
}

// Round 2
// 215.311 us; speedup vs baseline: 1.0170x; 1.0170x over previous
//
#include <hip/hip_runtime.h>
#include <float.h>

// FeatPropagation k=3 NN interpolation, round 7.
// R6 post-mortem: LDS staging regressed (156us): staging/addr added VALU
// (real busy 63->72us), 79KiB LDS halved blocks/CU (occ 61->38), and 16K
// wave-uniform ds_read_b128/CU serialized on the shared DS pipe. In BOTH
// R5/R6 real VALU time == computed floor (~65us) and ~80us is stall from
// point-stream wait granularity (SMEM lgkmcnt(0) drains / DS pipe).
// R7: (a) 2 queries per lane -> wave-level point iterations, loads and waits
// HALVE (total lane-evals fixed); (b) uniform-address per-lane VMEM loads
// (counted, in-order vmcnt -> real double-buffering; 8-pt group = ~550cy
// work >= L2 latency); (c) query-pair math as float2 with contract(off)
// (bit-identical per component, eligible for v_pk_*_f32 dual-issue).
//
// PROTECTED (absmax 0.015625, 4.7x under threshold): d2 computed as
// (q2+s2) - 2*((qx*sx+qy*sy)+qz*sz) with per-op f32 rounding (no fma, no
// reassociation) in this exact order; strict < via packed (d2,idx) f64 key
// min; ties -> lower index. Do NOT switch to fma/dx^2 form.

#define QPL   2     // queries per lane
#define QPB   128   // queries per block = 64 * QPL
#define SPLIT 8     // candidate chunks per block == waves per block
#define KEY_INIT 0x7FEFFFFFFFFFFFFFULL  // > any real packed key

typedef float v2f __attribute__((ext_vector_type(2)));

__global__ void pack_pts(const float* __restrict__ xyz,
                         float4* __restrict__ pts, int total) {
    int i = blockIdx.x * blockDim.x + threadIdx.x;
    if (i < total) {
        const float sx = xyz[(size_t)i * 3 + 0];
        const float sy = xyz[(size_t)i * 3 + 1];
        const float sz = xyz[(size_t)i * 3 + 2];
        const float s2 = __fadd_rn(__fadd_rn(__fmul_rn(sx, sx), __fmul_rn(sy, sy)),
                                   __fmul_rn(sz, sz));
        pts[i] = make_float4(sx, sy, sz, s2);
    }
}

__device__ __forceinline__ double mk_key(float d2, int j) {
    unsigned long long u =
        ((unsigned long long)(unsigned)__float_as_uint(d2) << 32) | (unsigned)j;
    return __longlong_as_double(u);
}

template <int CHUNK>
__global__ __launch_bounds__(512, 4) void fp_knn_main(
    const float* __restrict__ new_xyz,   // [B*M, 3]
    const float4* __restrict__ pts,      // [B*N] packed (x,y,z,s2)
    const float4* __restrict__ feat4,    // [B*N, 64]  (C=256)
    float4* __restrict__ out4,           // [B*M, 64]
    int N, int blocks_per_batch)
{
    __shared__ double s_k[SPLIT][QPB][3];   // 24 KiB
    __shared__ float  s_w[QPB][3];
    __shared__ int    s_j[QPB][3];

    int g = blockIdx.x;
    // XCD swizzle (bijective, grid 512): batch b's 128 blocks -> XCDs {2b,2b+1}
    // so its 4 MiB feat slab stays in one XCD pair's L2.
    if (gridDim.x == 512 && blocks_per_batch == 128) {
        const int xcd = g & 7, slot = g >> 3;        // slot in [0,64)
        g = (xcd >> 1) * 128 + (xcd & 1) * 64 + slot;
    }

    const int tid  = threadIdx.x;
    const int lane = tid & 63;
    const int b    = g / blocks_per_batch;
    const int src_base = b * N;
    const int m0 = g * QPB + lane;   // query 0 of this lane
    const int m1 = m0 + 64;          // query 1 of this lane

    const float q0x = new_xyz[(size_t)m0 * 3 + 0];
    const float q0y = new_xyz[(size_t)m0 * 3 + 1];
    const float q0z = new_xyz[(size_t)m0 * 3 + 2];
    const float q1x = new_xyz[(size_t)m1 * 3 + 0];
    const float q1y = new_xyz[(size_t)m1 * 3 + 1];
    const float q1z = new_xyz[(size_t)m1 * 3 + 2];
    const float q02 = __fadd_rn(__fadd_rn(__fmul_rn(q0x, q0x), __fmul_rn(q0y, q0y)),
                                __fmul_rn(q0z, q0z));
    const float q12 = __fadd_rn(__fadd_rn(__fmul_rn(q1x, q1x), __fmul_rn(q1y, q1y)),
                                __fmul_rn(q1z, q1z));
    const v2f qx2 = {q0x, q1x};
    const v2f qy2 = {q0y, q1y};
    const v2f qz2 = {q0z, q1z};
    const v2f q22 = {q02, q12};

    // Per-wave chunk. cw derives from tid (formally divergent) so the point
    // stream stays per-lane VMEM: 64 identical addresses coalesce to one
    // broadcast request, and vmcnt is counted+in-order -> the double buffer
    // actually pipelines (unlike SMEM's out-of-order lgkm).
    const int cw    = tid >> 6;          // 0..7
    const int cbase = cw * CHUNK;
    const float4* __restrict__ cp = pts + src_base + cbase;

    double k00 = __longlong_as_double(KEY_INIT);
    double k01 = k00, k02 = k00;
    double k10 = k00, k11 = k00, k12 = k00;

    constexpr int G  = 8;
    constexpr int NG = CHUNK / G;        // 64 groups
    float4 buf[2][G];

    #pragma unroll
    for (int t = 0; t < G; ++t) buf[0][t] = cp[t];

    auto process = [&](const float4 p, int cj) {
        #pragma clang fp contract(off)
        const v2f px = {p.x, p.x};
        const v2f py = {p.y, p.y};
        const v2f pz = {p.z, p.z};
        const v2f pw = {p.w, p.w};
        const v2f t0 = qx2 * px;
        const v2f t1 = qy2 * py;
        const v2f t2 = t0 + t1;
        const v2f t3 = qz2 * pz;
        const v2f cr = t2 + t3;
        const v2f qs = q22 + pw;
        const v2f cc = cr + cr;
        const v2f d2 = qs - cc;
        const double ka = mk_key(d2.x, cj);
        const double kb = mk_key(d2.y, cj);
        const double a0 = fmin(ka, k00);
        const double a1 = fmin(fmax(ka, k00), k01);
        const double a2 = fmin(fmax(ka, k01), k02);
        k00 = a0; k01 = a1; k02 = a2;
        const double b0 = fmin(kb, k10);
        const double b1 = fmin(fmax(kb, k10), k11);
        const double b2 = fmin(fmax(kb, k11), k12);
        k10 = b0; k11 = b1; k12 = b2;
    };

    #pragma unroll 2
    for (int gi = 0; gi < NG - 1; ++gi) {
        const float4* nx = cp + (gi + 1) * G;
        #pragma unroll
        for (int t = 0; t < G; ++t) buf[(gi + 1) & 1][t] = nx[t];
        #pragma unroll
        for (int t = 0; t < G; ++t)
            process(buf[gi & 1][t], cbase + gi * G + t);
    }
    #pragma unroll
    for (int t = 0; t < G; ++t)
        process(buf[(NG - 1) & 1][t], cbase + (NG - 1) * G + t);

    s_k[cw][lane][0]      = k00; s_k[cw][lane][1]      = k01; s_k[cw][lane][2]      = k02;
    s_k[cw][lane + 64][0] = k10; s_k[cw][lane + 64][1] = k11; s_k[cw][lane + 64][2] = k12;
    __syncthreads();

    // ---- 24-way merge per query on packed keys (2 waves, tie-exact) ----
    if (tid < QPB) {
        double m0k = __longlong_as_double(KEY_INIT), m1k = m0k, m2k = m0k;
        #pragma unroll
        for (int ss = 0; ss < SPLIT; ++ss) {
            #pragma unroll
            for (int r = 0; r < 3; ++r) {
                const double d = s_k[ss][tid][r];
                const double n0 = fmin(d, m0k);
                const double n1 = fmin(fmax(d, m0k), m1k);
                const double n2 = fmin(fmax(d, m1k), m2k);
                m0k = n0; m1k = n1; m2k = n2;
            }
        }
        unsigned long long u0 = __double_as_longlong(m0k);
        unsigned long long u1 = __double_as_longlong(m1k);
        unsigned long long u2 = __double_as_longlong(m2k);
        const float d0 = __uint_as_float((unsigned)(u0 >> 32));
        const float d1 = __uint_as_float((unsigned)(u1 >> 32));
        const float d2 = __uint_as_float((unsigned)(u2 >> 32));
        const float e0 = sqrtf(fmaxf(d0, 1e-12f));
        const float e1 = sqrtf(fmaxf(d1, 1e-12f));
        const float e2 = sqrtf(fmaxf(d2, 1e-12f));
        const float r0 = 1.0f / (e0 + 1e-8f);
        const float r1 = 1.0f / (e1 + 1e-8f);
        const float r2 = 1.0f / (e2 + 1e-8f);
        const float rs = r0 + r1 + r2;
        s_w[tid][0] = r0 / rs; s_w[tid][1] = r1 / rs; s_w[tid][2] = r2 / rs;
        s_j[tid][0] = (int)(u0 & 0xffffffffu);
        s_j[tid][1] = (int)(u1 & 0xffffffffu);
        s_j[tid][2] = (int)(u2 & 0xffffffffu);
    }
    __syncthreads();

    // ---- phase B: gather + interpolate; each of 8 waves handles 16 queries ----
    const int wv    = tid >> 6;
    const int qbase = g * QPB;
    #pragma unroll 4
    for (int t = 0; t < QPB / SPLIT; ++t) {
        const int qq = wv * (QPB / SPLIT) + t;
        const int   a0 = s_j[qq][0], a1 = s_j[qq][1], a2 = s_j[qq][2];
        const float u0 = s_w[qq][0], u1 = s_w[qq][1], u2 = s_w[qq][2];
        const float4 f0 = feat4[(size_t)(src_base + a0) * 64 + lane];
        const float4 f1 = feat4[(size_t)(src_base + a1) * 64 + lane];
        const float4 f2 = feat4[(size_t)(src_base + a2) * 64 + lane];
        float4 o;
        o.x = u0 * f0.x + u1 * f1.x + u2 * f2.x;
        o.y = u0 * f0.y + u1 * f1.y + u2 * f2.y;
        o.z = u0 * f0.z + u1 * f1.z + u2 * f2.z;
        o.w = u0 * f0.w + u1 * f1.w + u2 * f2.w;
        out4[(size_t)(qbase + qq) * 64 + lane] = o;
    }
}

// Generic fallback (shape mismatch only) — same semantics, unoptimized.
__global__ void fp_knn_generic(
    const float* __restrict__ new_xyz, const float* __restrict__ xyz,
    const float* __restrict__ feat, float* __restrict__ out,
    int N, int M, int Btot)
{
    const int m = blockIdx.x * blockDim.x + threadIdx.x;
    if (m >= Btot * M) return;
    const int b = m / M;
    const int src_base = b * N;
    const float qx = new_xyz[(size_t)m * 3 + 0];
    const float qy = new_xyz[(size_t)m * 3 + 1];
    const float qz = new_xyz[(size_t)m * 3 + 2];
    const float q2 = __fadd_rn(__fadd_rn(__fmul_rn(qx, qx), __fmul_rn(qy, qy)),
                               __fmul_rn(qz, qz));
    double k0 = __longlong_as_double(KEY_INIT), k1 = k0, k2 = k0;
    for (int j = 0; j < N; ++j) {
        const float sx = xyz[(size_t)(src_base + j) * 3 + 0];
        const float sy = xyz[(size_t)(src_base + j) * 3 + 1];
        const float sz = xyz[(size_t)(src_base + j) * 3 + 2];
        const float s2 = __fadd_rn(__fadd_rn(__fmul_rn(sx, sx), __fmul_rn(sy, sy)),
                                   __fmul_rn(sz, sz));
        const float cross = __fadd_rn(
            __fadd_rn(__fmul_rn(qx, sx), __fmul_rn(qy, sy)), __fmul_rn(qz, sz));
        const float d2 = __fadd_rn(q2, s2) - (cross + cross);
        const double key = mk_key(d2, j);
        const double n0 = fmin(key, k0);
        const double n1 = fmin(fmax(key, k0), k1);
        const double n2 = fmin(fmax(key, k1), k2);
        k0 = n0; k1 = n1; k2 = n2;
    }
    unsigned long long u0 = __double_as_longlong(k0);
    unsigned long long u1 = __double_as_longlong(k1);
    unsigned long long u2 = __double_as_longlong(k2);
    const float e0 = sqrtf(fmaxf(__uint_as_float((unsigned)(u0 >> 32)), 1e-12f));
    const float e1 = sqrtf(fmaxf(__uint_as_float((unsigned)(u1 >> 32)), 1e-12f));
    const float e2 = sqrtf(fmaxf(__uint_as_float((unsigned)(u2 >> 32)), 1e-12f));
    const float r0 = 1.0f / (e0 + 1e-8f);
    const float r1 = 1.0f / (e1 + 1e-8f);
    const float r2 = 1.0f / (e2 + 1e-8f);
    const float rs = r0 + r1 + r2;
    const float w0 = r0 / rs, w1 = r1 / rs, w2 = r2 / rs;
    const int a0 = (int)(u0 & 0xffffffffu), a1 = (int)(u1 & 0xffffffffu),
              a2 = (int)(u2 & 0xffffffffu);
    const int C = 256;
    for (int c = 0; c < C; ++c) {
        out[(size_t)m * C + c] =
            w0 * feat[(size_t)(src_base + a0) * C + c] +
            w1 * feat[(size_t)(src_base + a1) * C + c] +
            w2 * feat[(size_t)(src_base + a2) * C + c];
    }
}

extern "C" void kernel_launch(void* const* d_in, const int* in_sizes, int n_in,
                              void* d_out, int out_size, void* d_ws, size_t ws_size,
                              hipStream_t stream) {
    const float* xyz     = (const float*)d_in[0];
    const float* new_xyz = (const float*)d_in[1];
    const float* feat    = (const float*)d_in[2];
    float* out = (float*)d_out;

    const int B = in_sizes[3];                 // 4
    const int N = in_sizes[0] / (3 * B);       // 4096
    const int M = in_sizes[1] / (3 * B);       // 16384

    const size_t need = (size_t)(B * N) * sizeof(float4);  // 256 KiB
    const bool fast = (N % SPLIT == 0) && (N / SPLIT == 512) &&
                      (M % QPB == 0) && (ws_size >= need);
    if (fast) {
        pack_pts<<<(B * N + 255) / 256, 256, 0, stream>>>(xyz, (float4*)d_ws, B * N);
        const int blocks = (B * M) / QPB;      // 512
        fp_knn_main<512><<<blocks, 512, 0, stream>>>(
            new_xyz, (const float4*)d_ws, (const float4*)feat, (float4*)out,
            N, M / QPB);
    } else {
        fp_knn_generic<<<(B * M + 255) / 256, 256, 0, stream>>>(
            new_xyz, xyz, feat, out, N, M, B);
    }
}

// Round 3
// 210.524 us; speedup vs baseline: 1.0401x; 1.0227x over previous
//
#include <hip/hip_runtime.h>
#include <float.h>

// FeatPropagation k=3 NN interpolation, round 8.
// R7 post-mortem: VGPR_Count=48 < 64 regs needed for buf[2][8] -> the double
// buffer lived in SCRATCH, not registers (two-level runtime-ish indexing under
// partial unroll defeated promotion; rule #20). The vmcnt pipeline never
// existed; raw VALUBusy fell 86->72 as waves waited on scratch round-trips.
// Same forensic holds for R5 (VGPR 24 < 32). R8: identical algorithm to R7
// (QPL=2, G=8, per-lane broadcast VMEM, counted vmcnt), but the stream buffer
// is two explicitly ping-ponged banks A[8]/B[8] touched ONLY under fully
// unrolled compile-time indices. Verify via VGPR_Count ~100-126.
//
// PROTECTED (absmax 0.015625, 4.7x under threshold): d2 computed as
// (q2+s2) - 2*((qx*sx+qy*sy)+qz*sz) with per-op f32 rounding (no fma, no
// reassociation) in this exact order; strict < via packed (d2,idx) f64 key
// min; ties -> lower index. Do NOT switch to fma/dx^2 form.

#define QPL   2     // queries per lane
#define QPB   128   // queries per block = 64 * QPL
#define SPLIT 8     // candidate chunks per block == waves per block
#define KEY_INIT 0x7FEFFFFFFFFFFFFFULL  // > any real packed key

typedef float v2f __attribute__((ext_vector_type(2)));

__global__ void pack_pts(const float* __restrict__ xyz,
                         float4* __restrict__ pts, int total) {
    int i = blockIdx.x * blockDim.x + threadIdx.x;
    if (i < total) {
        const float sx = xyz[(size_t)i * 3 + 0];
        const float sy = xyz[(size_t)i * 3 + 1];
        const float sz = xyz[(size_t)i * 3 + 2];
        const float s2 = __fadd_rn(__fadd_rn(__fmul_rn(sx, sx), __fmul_rn(sy, sy)),
                                   __fmul_rn(sz, sz));
        pts[i] = make_float4(sx, sy, sz, s2);
    }
}

__device__ __forceinline__ double mk_key(float d2, int j) {
    unsigned long long u =
        ((unsigned long long)(unsigned)__float_as_uint(d2) << 32) | (unsigned)j;
    return __longlong_as_double(u);
}

template <int CHUNK>
__global__ __launch_bounds__(512, 4) void fp_knn_main(
    const float* __restrict__ new_xyz,   // [B*M, 3]
    const float4* __restrict__ pts,      // [B*N] packed (x,y,z,s2)
    const float4* __restrict__ feat4,    // [B*N, 64]  (C=256)
    float4* __restrict__ out4,           // [B*M, 64]
    int N, int blocks_per_batch)
{
    __shared__ double s_k[SPLIT][QPB][3];   // 24 KiB
    __shared__ float  s_w[QPB][3];
    __shared__ int    s_j[QPB][3];

    int g = blockIdx.x;
    // XCD swizzle (bijective, grid 512): batch b's 128 blocks -> XCDs {2b,2b+1}
    // so its 4 MiB feat slab stays in one XCD pair's L2.
    if (gridDim.x == 512 && blocks_per_batch == 128) {
        const int xcd = g & 7, slot = g >> 3;        // slot in [0,64)
        g = (xcd >> 1) * 128 + (xcd & 1) * 64 + slot;
    }

    const int tid  = threadIdx.x;
    const int lane = tid & 63;
    const int b    = g / blocks_per_batch;
    const int src_base = b * N;
    const int m0 = g * QPB + lane;   // query 0 of this lane
    const int m1 = m0 + 64;          // query 1 of this lane

    const float q0x = new_xyz[(size_t)m0 * 3 + 0];
    const float q0y = new_xyz[(size_t)m0 * 3 + 1];
    const float q0z = new_xyz[(size_t)m0 * 3 + 2];
    const float q1x = new_xyz[(size_t)m1 * 3 + 0];
    const float q1y = new_xyz[(size_t)m1 * 3 + 1];
    const float q1z = new_xyz[(size_t)m1 * 3 + 2];
    const float q02 = __fadd_rn(__fadd_rn(__fmul_rn(q0x, q0x), __fmul_rn(q0y, q0y)),
                                __fmul_rn(q0z, q0z));
    const float q12 = __fadd_rn(__fadd_rn(__fmul_rn(q1x, q1x), __fmul_rn(q1y, q1y)),
                                __fmul_rn(q1z, q1z));
    const v2f qx2 = {q0x, q1x};
    const v2f qy2 = {q0y, q1y};
    const v2f qz2 = {q0z, q1z};
    const v2f q22 = {q02, q12};

    // Per-wave chunk. cw derives from tid (formally divergent) so the point
    // stream stays per-lane VMEM: 64 identical addresses coalesce to one
    // broadcast request, and vmcnt is counted+in-order -> the ping-pong banks
    // actually pipeline (unlike SMEM's out-of-order lgkm).
    const int cw    = tid >> 6;          // 0..7
    const int cbase = cw * CHUNK;
    const float4* __restrict__ cp = pts + src_base + cbase;

    double k00 = __longlong_as_double(KEY_INIT);
    double k01 = k00, k02 = k00;
    double k10 = k00, k11 = k00, k12 = k00;

    constexpr int G  = 8;
    constexpr int NG = CHUNK / G;        // 64 groups (even)

    // Explicit register banks: touched ONLY with compile-time indices.
    float4 A[G], B[G];

    auto process = [&](const float4 p, int cj) {
        #pragma clang fp contract(off)
        const v2f px = {p.x, p.x};
        const v2f py = {p.y, p.y};
        const v2f pz = {p.z, p.z};
        const v2f pw = {p.w, p.w};
        const v2f t0 = qx2 * px;
        const v2f t1 = qy2 * py;
        const v2f t2 = t0 + t1;
        const v2f t3 = qz2 * pz;
        const v2f cr = t2 + t3;
        const v2f qs = q22 + pw;
        const v2f cc = cr + cr;
        const v2f d2 = qs - cc;
        const double ka = mk_key(d2.x, cj);
        const double kb = mk_key(d2.y, cj);
        const double a0 = fmin(ka, k00);
        const double a1 = fmin(fmax(ka, k00), k01);
        const double a2 = fmin(fmax(ka, k01), k02);
        k00 = a0; k01 = a1; k02 = a2;
        const double b0 = fmin(kb, k10);
        const double b1 = fmin(fmax(kb, k10), k11);
        const double b2 = fmin(fmax(kb, k11), k12);
        k10 = b0; k11 = b1; k12 = b2;
    };

    // Prologue: bank A <- group 0.
    #pragma unroll
    for (int t = 0; t < G; ++t) A[t] = cp[t];

    // Ping-pong main loop: load B(gi+1); process A(gi); load A(gi+2);
    // process B(gi+1). All bank indices compile-time.
    int gi = 0;
    for (; gi < NG - 2; gi += 2) {
        const float4* nx1 = cp + (gi + 1) * G;
        #pragma unroll
        for (int t = 0; t < G; ++t) B[t] = nx1[t];
        #pragma unroll
        for (int t = 0; t < G; ++t) process(A[t], cbase + gi * G + t);
        const float4* nx2 = cp + (gi + 2) * G;
        #pragma unroll
        for (int t = 0; t < G; ++t) A[t] = nx2[t];
        #pragma unroll
        for (int t = 0; t < G; ++t) process(B[t], cbase + (gi + 1) * G + t);
    }
    // Tail: gi == NG-2.
    {
        const float4* nx1 = cp + (gi + 1) * G;
        #pragma unroll
        for (int t = 0; t < G; ++t) B[t] = nx1[t];
        #pragma unroll
        for (int t = 0; t < G; ++t) process(A[t], cbase + gi * G + t);
        #pragma unroll
        for (int t = 0; t < G; ++t) process(B[t], cbase + (gi + 1) * G + t);
    }

    s_k[cw][lane][0]      = k00; s_k[cw][lane][1]      = k01; s_k[cw][lane][2]      = k02;
    s_k[cw][lane + 64][0] = k10; s_k[cw][lane + 64][1] = k11; s_k[cw][lane + 64][2] = k12;
    __syncthreads();

    // ---- 24-way merge per query on packed keys (2 waves, tie-exact) ----
    if (tid < QPB) {
        double m0k = __longlong_as_double(KEY_INIT), m1k = m0k, m2k = m0k;
        #pragma unroll
        for (int ss = 0; ss < SPLIT; ++ss) {
            #pragma unroll
            for (int r = 0; r < 3; ++r) {
                const double d = s_k[ss][tid][r];
                const double n0 = fmin(d, m0k);
                const double n1 = fmin(fmax(d, m0k), m1k);
                const double n2 = fmin(fmax(d, m1k), m2k);
                m0k = n0; m1k = n1; m2k = n2;
            }
        }
        unsigned long long u0 = __double_as_longlong(m0k);
        unsigned long long u1 = __double_as_longlong(m1k);
        unsigned long long u2 = __double_as_longlong(m2k);
        const float d0 = __uint_as_float((unsigned)(u0 >> 32));
        const float d1 = __uint_as_float((unsigned)(u1 >> 32));
        const float d2 = __uint_as_float((unsigned)(u2 >> 32));
        const float e0 = sqrtf(fmaxf(d0, 1e-12f));
        const float e1 = sqrtf(fmaxf(d1, 1e-12f));
        const float e2 = sqrtf(fmaxf(d2, 1e-12f));
        const float r0 = 1.0f / (e0 + 1e-8f);
        const float r1 = 1.0f / (e1 + 1e-8f);
        const float r2 = 1.0f / (e2 + 1e-8f);
        const float rs = r0 + r1 + r2;
        s_w[tid][0] = r0 / rs; s_w[tid][1] = r1 / rs; s_w[tid][2] = r2 / rs;
        s_j[tid][0] = (int)(u0 & 0xffffffffu);
        s_j[tid][1] = (int)(u1 & 0xffffffffu);
        s_j[tid][2] = (int)(u2 & 0xffffffffu);
    }
    __syncthreads();

    // ---- phase B: gather + interpolate; each of 8 waves handles 16 queries ----
    const int wv    = tid >> 6;
    const int qbase = g * QPB;
    #pragma unroll 4
    for (int t = 0; t < QPB / SPLIT; ++t) {
        const int qq = wv * (QPB / SPLIT) + t;
        const int   a0 = s_j[qq][0], a1 = s_j[qq][1], a2 = s_j[qq][2];
        const float u0 = s_w[qq][0], u1 = s_w[qq][1], u2 = s_w[qq][2];
        const float4 f0 = feat4[(size_t)(src_base + a0) * 64 + lane];
        const float4 f1 = feat4[(size_t)(src_base + a1) * 64 + lane];
        const float4 f2 = feat4[(size_t)(src_base + a2) * 64 + lane];
        float4 o;
        o.x = u0 * f0.x + u1 * f1.x + u2 * f2.x;
        o.y = u0 * f0.y + u1 * f1.y + u2 * f2.y;
        o.z = u0 * f0.z + u1 * f1.z + u2 * f2.z;
        o.w = u0 * f0.w + u1 * f1.w + u2 * f2.w;
        out4[(size_t)(qbase + qq) * 64 + lane] = o;
    }
}

// Generic fallback (shape mismatch only) — same semantics, unoptimized.
__global__ void fp_knn_generic(
    const float* __restrict__ new_xyz, const float* __restrict__ xyz,
    const float* __restrict__ feat, float* __restrict__ out,
    int N, int M, int Btot)
{
    const int m = blockIdx.x * blockDim.x + threadIdx.x;
    if (m >= Btot * M) return;
    const int b = m / M;
    const int src_base = b * N;
    const float qx = new_xyz[(size_t)m * 3 + 0];
    const float qy = new_xyz[(size_t)m * 3 + 1];
    const float qz = new_xyz[(size_t)m * 3 + 2];
    const float q2 = __fadd_rn(__fadd_rn(__fmul_rn(qx, qx), __fmul_rn(qy, qy)),
                               __fmul_rn(qz, qz));
    double k0 = __longlong_as_double(KEY_INIT), k1 = k0, k2 = k0;
    for (int j = 0; j < N; ++j) {
        const float sx = xyz[(size_t)(src_base + j) * 3 + 0];
        const float sy = xyz[(size_t)(src_base + j) * 3 + 1];
        const float sz = xyz[(size_t)(src_base + j) * 3 + 2];
        const float s2 = __fadd_rn(__fadd_rn(__fmul_rn(sx, sx), __fmul_rn(sy, sy)),
                                   __fmul_rn(sz, sz));
        const float cross = __fadd_rn(
            __fadd_rn(__fmul_rn(qx, sx), __fmul_rn(qy, sy)), __fmul_rn(qz, sz));
        const float d2 = __fadd_rn(q2, s2) - (cross + cross);
        const double key = mk_key(d2, j);
        const double n0 = fmin(key, k0);
        const double n1 = fmin(fmax(key, k0), k1);
        const double n2 = fmin(fmax(key, k1), k2);
        k0 = n0; k1 = n1; k2 = n2;
    }
    unsigned long long u0 = __double_as_longlong(k0);
    unsigned long long u1 = __double_as_longlong(k1);
    unsigned long long u2 = __double_as_longlong(k2);
    const float e0 = sqrtf(fmaxf(__uint_as_float((unsigned)(u0 >> 32)), 1e-12f));
    const float e1 = sqrtf(fmaxf(__uint_as_float((unsigned)(u1 >> 32)), 1e-12f));
    const float e2 = sqrtf(fmaxf(__uint_as_float((unsigned)(u2 >> 32)), 1e-12f));
    const float r0 = 1.0f / (e0 + 1e-8f);
    const float r1 = 1.0f / (e1 + 1e-8f);
    const float r2 = 1.0f / (e2 + 1e-8f);
    const float rs = r0 + r1 + r2;
    const float w0 = r0 / rs, w1 = r1 / rs, w2 = r2 / rs;
    const int a0 = (int)(u0 & 0xffffffffu), a1 = (int)(u1 & 0xffffffffu),
              a2 = (int)(u2 & 0xffffffffu);
    const int C = 256;
    for (int c = 0; c < C; ++c) {
        out[(size_t)m * C + c] =
            w0 * feat[(size_t)(src_base + a0) * C + c] +
            w1 * feat[(size_t)(src_base + a1) * C + c] +
            w2 * feat[(size_t)(src_base + a2) * C + c];
    }
}

extern "C" void kernel_launch(void* const* d_in, const int* in_sizes, int n_in,
                              void* d_out, int out_size, void* d_ws, size_t ws_size,
                              hipStream_t stream) {
    const float* xyz     = (const float*)d_in[0];
    const float* new_xyz = (const float*)d_in[1];
    const float* feat    = (const float*)d_in[2];
    float* out = (float*)d_out;

    const int B = in_sizes[3];                 // 4
    const int N = in_sizes[0] / (3 * B);       // 4096
    const int M = in_sizes[1] / (3 * B);       // 16384

    const size_t need = (size_t)(B * N) * sizeof(float4);  // 256 KiB
    const bool fast = (N % SPLIT == 0) && (N / SPLIT == 512) &&
                      (M % QPB == 0) && (ws_size >= need);
    if (fast) {
        pack_pts<<<(B * N + 255) / 256, 256, 0, stream>>>(xyz, (float4*)d_ws, B * N);
        const int blocks = (B * M) / QPB;      // 512
        fp_knn_main<512><<<blocks, 512, 0, stream>>>(
            new_xyz, (const float4*)d_ws, (const float4*)feat, (float4*)out,
            N, M / QPB);
    } else {
        fp_knn_generic<<<(B * M + 255) / 256, 256, 0, stream>>>(
            new_xyz, xyz, feat, out, N, M, B);
    }
}